// Round 3
// baseline (85.320 us; speedup 1.0000x reference)
//
#include <hip/hip_runtime.h>

// AdderNet 2D: out[n,f,h,w] = -sum_{c,kh,kw} |W[f,c,kh,kw] - xpad[n,c,h+kh,w+kw]|
// x: (16,64,14,14) fp32, W: (64,64,3,3) fp32, out: (16,64,14,14) fp32
//
// R3: channel-contiguous LDS layout. xt[pix][CPAD] with pix = padded
// (row*16+col), CPAD=68 (16B-aligned, bank-group spread (17*pix+g)%8 ->
// uniform -> conflict-free b128). Compute reads 4 channels per
// ds_read_b128; all 9 window offsets are immediates off one base VGPR.
// 144 b128/thread vs 576 b32 in R2 -> LDS 2.9us < VALU 3.84us floor.

#define N_ 16
#define C_ 64
#define F_ 64
#define P_ 196
#define CPAD 68
#define NT 4   // filters per block

__global__ __launch_bounds__(256) void adder2d_kernel(
    const float* __restrict__ x, const float* __restrict__ w,
    float* __restrict__ out)
{
    __shared__ __align__(16) float xt[256 * CPAD];  // 69,632 B

    const int tid = threadIdx.x;
    const int fg  = blockIdx.x;   // 0..15 -> filters fg*4..fg*4+3
    const int n   = blockIdx.y;   // 0..15

    // ---- zero whole tile (covers halo), linear b128 stores ----
    float4* xt4 = (float4*)xt;
    #pragma unroll
    for (int i = 0; i < 17; ++i)   // 17*256 = 4352 float4 = 17408 floats
        xt4[i * 256 + tid] = make_float4(0.f, 0.f, 0.f, 0.f);
    __syncthreads();

    // ---- stage interior: lane = channel, so LDS stores are addr=pix*68+c
    //      -> across lanes c spans 0..63 -> 2 lanes/bank (free). ----
    {
        const int c  = tid & 63;   // channel
        const int wq = tid >> 6;   // wave's q-phase 0..3
        const float4* x4 = (const float4*)(x + (n * C_ + c) * P_);
        #pragma unroll
        for (int i = 0; i < 13; ++i) {
            const int q = wq + 4 * i;   // float4 index within channel, 0..48
            if (q < 49) {
                float4 v = x4[q];
                float vv[4] = {v.x, v.y, v.z, v.w};
                const int e = 4 * q;
                #pragma unroll
                for (int j = 0; j < 4; ++j) {
                    const int ee  = e + j;        // pixel 0..195
                    const int r   = ee / 14;
                    const int col = ee - r * 14;
                    xt[((r + 1) * 16 + (col + 1)) * CPAD + c] = vv[j];
                }
            }
        }
    }
    __syncthreads();

    // ---- compute: 1 pixel x 4 filters per thread ----
    if (tid < P_) {
        const int h  = tid / 14;
        const int wv = tid - h * 14;
        const int fbase = fg * NT;
        const float* wp = w + fbase * (C_ * 9);   // block-uniform -> s_load

        float acc0 = 0.f, acc1 = 0.f, acc2 = 0.f, acc3 = 0.f;
        const float* base = xt + (h * 16 + wv) * CPAD;  // window (0,0) base

        #pragma unroll 2
        for (int g = 0; g < 16; ++g) {   // channel group: c = 4g..4g+3
            float4 xv[9];
            #pragma unroll
            for (int kh = 0; kh < 3; ++kh)
                #pragma unroll
                for (int kw = 0; kw < 3; ++kw)
                    xv[kh * 3 + kw] =
                        *(const float4*)(base + (kh * 16 + kw) * CPAD + 4 * g);

            // W[f][c][kk] = wp[f*576 + c*9 + kk], uniform -> SGPR
            #pragma unroll
            for (int f = 0; f < 4; ++f) {
                const float* wf = wp + f * (C_ * 9) + (4 * g) * 9;
                float a = 0.f;
                #pragma unroll
                for (int kk = 0; kk < 9; ++kk) {
                    a += fabsf(wf[0 * 9 + kk] - xv[kk].x)
                       + fabsf(wf[1 * 9 + kk] - xv[kk].y)
                       + fabsf(wf[2 * 9 + kk] - xv[kk].z)
                       + fabsf(wf[3 * 9 + kk] - xv[kk].w);
                }
                if (f == 0) acc0 += a;
                else if (f == 1) acc1 += a;
                else if (f == 2) acc2 += a;
                else acc3 += a;
            }
        }

        float* op = out + (n * F_ + fbase) * P_ + tid;
        op[0 * P_] = -acc0;
        op[1 * P_] = -acc1;
        op[2 * P_] = -acc2;
        op[3 * P_] = -acc3;
    }
}

extern "C" void kernel_launch(void* const* d_in, const int* in_sizes, int n_in,
                              void* d_out, int out_size, void* d_ws, size_t ws_size,
                              hipStream_t stream) {
    const float* x = (const float*)d_in[0];
    const float* w = (const float*)d_in[1];
    float* out = (float*)d_out;
    dim3 grid(F_ / NT, N_);
    adder2d_kernel<<<grid, 256, 0, stream>>>(x, w, out);
}

// Round 4
// 69.496 us; speedup vs baseline: 1.2277x; 1.2277x over previous
//
#include <hip/hip_runtime.h>

// AdderNet 2D: out[n,f,h,w] = -sum_{c,kh,kw} |W[f,c,kh,kw] - xpad[n,c,h+kh,w+kw]|
// x: (16,64,14,14) fp32, W: (64,64,3,3) fp32, out: (16,64,14,14) fp32
//
// R4: same channel-contiguous LDS layout as R3 (xt[padded_px][CPAD=68],
// conflict-free b128 reads), but 1024-thread blocks: thread = (cq, px)
// where cq = wave-uniform channel-quarter (16 ch each). 16 waves/CU =
// 4 waves/SIMD (vs 1 in R3) to hide ds_read + W s_load latency.
// W reads stay block/wave-uniform -> scalar pipe. Final 4-way c-reduce
// through a small LDS float4 buffer.

#define N_ 16
#define C_ 64
#define F_ 64
#define P_ 196
#define CPAD 68
#define NT 4   // filters per block

__global__ __launch_bounds__(1024) void adder2d_kernel(
    const float* __restrict__ x, const float* __restrict__ w,
    float* __restrict__ out)
{
    __shared__ __align__(16) float xt[256 * CPAD];   // 69,632 B
    __shared__ __align__(16) float4 red[4][256];     // 16,384 B

    const int tid = threadIdx.x;      // 0..1023
    const int fg  = blockIdx.x;       // 0..15 -> filters fg*4..fg*4+3
    const int n   = blockIdx.y;       // 0..15

    // ---- zero whole tile (covers halo): 4352 float4 / 1024 thr ----
    float4* xt4 = (float4*)xt;
    #pragma unroll
    for (int i = 0; i < 5; ++i) {
        int idx = tid + i * 1024;
        if (idx < 4352) xt4[idx] = make_float4(0.f, 0.f, 0.f, 0.f);
    }
    __syncthreads();

    // ---- stage interior. lane = channel -> LDS store addr = px*68 + c
    //      (stride-1 across lanes, conflict-free). <=4 float4 loads/thread.
    {
        const int c     = tid & 63;
        const int phase = tid >> 6;   // 0..15
        const float4* x4 = (const float4*)(x + (n * C_ + c) * P_);
        #pragma unroll
        for (int i = 0; i < 4; ++i) {
            const int q = phase + 16 * i;   // float4 index within channel
            if (q < 49) {
                float4 v = x4[q];
                float vv[4] = {v.x, v.y, v.z, v.w};
                const int e = 4 * q;
                #pragma unroll
                for (int j = 0; j < 4; ++j) {
                    const int ee  = e + j;          // pixel 0..195
                    const int r   = ee / 14;
                    const int col = ee - r * 14;
                    xt[((r + 1) * 16 + (col + 1)) * CPAD + c] = vv[j];
                }
            }
        }
    }
    __syncthreads();

    // ---- compute: thread = (cq, px); cq wave-uniform -> scalar W loads ----
    const int cq = __builtin_amdgcn_readfirstlane(tid >> 8);  // 0..3
    const int px = tid & 255;                                 // 0..255
    const int fbase = fg * NT;
    const int cbase = cq * 16;

    float acc0 = 0.f, acc1 = 0.f, acc2 = 0.f, acc3 = 0.f;

    if (px < P_) {
        const int h  = px / 14;
        const int wv = px - h * 14;
        const float* bp = xt + (h * 16 + wv) * CPAD + cbase;

        #pragma unroll
        for (int g = 0; g < 4; ++g) {          // 4-channel groups
            const float* bg = bp + 4 * g;
            float4 xv[9];
            #pragma unroll
            for (int kh = 0; kh < 3; ++kh)
                #pragma unroll
                for (int kw = 0; kw < 3; ++kw)
                    xv[kh * 3 + kw] = *(const float4*)(bg + (kh * 16 + kw) * CPAD);

            // W[f][c][kk] = w[(fbase+f)*576 + c*9 + kk]; all uniform -> s_load
            #pragma unroll
            for (int f = 0; f < 4; ++f) {
                const float* wfp = w + (fbase + f) * (C_ * 9) + (cbase + 4 * g) * 9;
                float a = 0.f;
                #pragma unroll
                for (int kk = 0; kk < 9; ++kk) {
                    a += fabsf(wfp[0 * 9 + kk] - xv[kk].x)
                       + fabsf(wfp[1 * 9 + kk] - xv[kk].y)
                       + fabsf(wfp[2 * 9 + kk] - xv[kk].z)
                       + fabsf(wfp[3 * 9 + kk] - xv[kk].w);
                }
                if (f == 0) acc0 += a;
                else if (f == 1) acc1 += a;
                else if (f == 2) acc2 += a;
                else acc3 += a;
            }
        }
    }

    red[cq][px] = make_float4(acc0, acc1, acc2, acc3);
    __syncthreads();

    // ---- 4-way c-reduce + store ----
    if (tid < P_) {
        float4 r0 = red[0][tid];
        float4 r1 = red[1][tid];
        float4 r2 = red[2][tid];
        float4 r3 = red[3][tid];
        float o0 = r0.x + r1.x + r2.x + r3.x;
        float o1 = r0.y + r1.y + r2.y + r3.y;
        float o2 = r0.z + r1.z + r2.z + r3.z;
        float o3 = r0.w + r1.w + r2.w + r3.w;
        float* op = out + (n * F_ + fbase) * P_ + tid;
        op[0 * P_] = -o0;
        op[1 * P_] = -o1;
        op[2 * P_] = -o2;
        op[3 * P_] = -o3;
    }
}

extern "C" void kernel_launch(void* const* d_in, const int* in_sizes, int n_in,
                              void* d_out, int out_size, void* d_ws, size_t ws_size,
                              hipStream_t stream) {
    const float* x = (const float*)d_in[0];
    const float* w = (const float*)d_in[1];
    float* out = (float*)d_out;
    dim3 grid(F_ / NT, N_);
    adder2d_kernel<<<grid, 1024, 0, stream>>>(x, w, out);
}